// Round 10
// baseline (662.488 us; speedup 1.0000x reference)
//
#include <hip/hip_runtime.h>

#define BB 4
#define HH 512
#define WW 512
#define KK 7
#define PP 3
#define CC 256
#define RS 32                      // region is RS x RS
#define SD (RS + 2 * PP)           // 38 (region + halo)
#define NT 256                     // threads per block (4 waves)
#define NWAVE (NT / 64)            // 4
#define NREG (BB * (HH / RS) * (WW / RS))   // 1024
#define NCHUNK 4
#define CH4 16                     // float4 per 64-channel chunk
#define NBLK (NREG * NCHUNK)       // 4096

// Scatter active-site linear index into dense idx_map (pre-filled with -1).
__global__ void smconv_scatter(const int* __restrict__ idx,
                               int* __restrict__ idx_map, int n) {
    int i = blockIdx.x * blockDim.x + threadIdx.x;
    if (i >= n) return;
    int b = idx[i * 3 + 0];
    int y = idx[i * 3 + 1];
    int x = idx[i * 3 + 2];
    idx_map[((size_t)b * HH + y) * WW + x] = i;
}

// Transpose weight (C, K, K) -> (K*K, C) so per-tap channel rows are contiguous.
__global__ void smconv_wt(const float* __restrict__ w, float* __restrict__ w_t) {
    int i = blockIdx.x * blockDim.x + threadIdx.x;
    if (i >= KK * KK * CC) return;
    int tap = i / CC;
    int c = i - tap * CC;
    w_t[i] = w[c * KK * KK + tap];
}

// Lane = site, block = region x 64-channel chunk. Each lane owns one active
// site and iterates the 49 taps; per active tap it reads 16 imm-offset float4
// (256B aligned slice = 2 full cache lines) into a 64-VGPR accumulator.
// Weights/bias are wave-uniform -> scalar loads. No ballot/ffs/readlane
// scaffolding in the compute loop.
__global__ void __launch_bounds__(NT)
smconv_lane(const float* __restrict__ feat,
            const float* __restrict__ w_t,
            const float* __restrict__ bias,
            const int* __restrict__ idx_map,
            float* __restrict__ out) {
    __shared__ int smap[SD * SD];              // 5,776 B
    __shared__ unsigned short lst[RS * RS];    // 2,048 B
    __shared__ int wcnt[NWAVE];

    const int tid  = threadIdx.x;
    const int wave = tid >> 6;
    const int lane = tid & 63;

    // XCD-chunked swizzle: XCD k owns 512 consecutive work items; within a
    // slab, chunk varies fastest so a region's 4 chunk-blocks co-run.
    const int Wk    = (blockIdx.x & 7) * (NBLK / 8) + (blockIdx.x >> 3);
    const int reg   = Wk >> 2;
    const int chunk = Wk & 3;
    const int b  = reg >> 8;                   // 256 regions per batch
    const int rm = reg & 255;
    const int rx = rm >> 4;                    // 16 column strips
    const int ry = rm & 15;                    // y-adjacent regions consecutive
    const int y0 = ry * RS;
    const int x0 = rx * RS;

    // Stage region+halo idx_map into LDS (-1 outside image).
    for (int i = tid; i < SD * SD; i += NT) {
        int gy = y0 + i / SD - PP;
        int gx = x0 + i % SD - PP;
        int v = -1;
        if (gy >= 0 && gy < HH && gx >= 0 && gx < WW)
            v = idx_map[((size_t)b * HH + gy) * WW + gx];
        smap[i] = v;
    }
    __syncthreads();

    // Build active-site list in deterministic scan order (prefix via ballot).
    int total = 0;
    for (int c0 = 0; c0 < RS * RS; c0 += NT) {
        int i = c0 + tid;
        int iy = i >> 5;
        int ix = i & (RS - 1);
        bool act = smap[(iy + PP) * SD + (ix + PP)] >= 0;
        unsigned long long bal = __ballot(act);
        if (lane == 0) wcnt[wave] = __popcll(bal);
        __syncthreads();
        int off = total;
        for (int w = 0; w < wave; ++w) off += wcnt[w];
        if (act)
            lst[off + __popcll(bal & ((1ull << lane) - 1))] = (unsigned short)i;
        int t2 = total;
        for (int w = 0; w < NWAVE; ++w) t2 += wcnt[w];
        total = t2;
        __syncthreads();
    }

    const float4* feat4 = (const float4*)feat;
    const float4* wt4   = (const float4*)w_t;    // (tap, 64 float4)
    const float4* bias4 = (const float4*)bias;
    float4* out4 = (float4*)out;
    const int co = chunk * CH4;                  // float4 offset within a row

    // Lane = site: each thread processes whole sites independently.
    for (int s = tid; s < total; s += NT) {
        const int pos = lst[s];
        const int sb = (pos >> 5) * SD + (pos & (RS - 1));

        float4 acc[CH4];
        #pragma unroll
        for (int j = 0; j < CH4; ++j) acc[j] = bias4[co + j];

        int t64 = 0;   // tap * 64, strength-reduced
        for (int dy = 0; dy < KK; ++dy) {
            int rbase = sb + dy * SD;
            for (int dx = 0; dx < KK; ++dx, t64 += 64) {
                int nb = smap[rbase + dx];
                if (nb >= 0) {
                    const float4* frow = feat4 + (size_t)nb * (CC / 4) + co;
                    #pragma unroll
                    for (int j = 0; j < CH4; ++j) {
                        float4 f  = frow[j];            // imm-offset loads
                        float4 wv = wt4[t64 + co + j];  // wave-uniform -> s_load
                        acc[j].x = fmaf(f.x, wv.x, acc[j].x);
                        acc[j].y = fmaf(f.y, wv.y, acc[j].y);
                        acc[j].z = fmaf(f.z, wv.z, acc[j].z);
                        acc[j].w = fmaf(f.w, wv.w, acc[j].w);
                    }
                }
            }
        }

        const int row = smap[sb + PP * SD + PP];    // own id (center tap)
        float4* orow = out4 + (size_t)row * (CC / 4) + co;
        #pragma unroll
        for (int j = 0; j < CH4; ++j) orow[j] = acc[j];
    }
}

extern "C" void kernel_launch(void* const* d_in, const int* in_sizes, int n_in,
                              void* d_out, int out_size, void* d_ws, size_t ws_size,
                              hipStream_t stream) {
    const float* feat = (const float*)d_in[0];
    const int*   idx  = (const int*)d_in[1];
    const float* w    = (const float*)d_in[2];
    const float* bias = (const float*)d_in[3];
    float* out = (float*)d_out;

    const int n = in_sizes[0] / CC;  // number of active sites

    int*   idx_map = (int*)d_ws;
    float* w_t     = (float*)((char*)d_ws + (size_t)BB * HH * WW * sizeof(int));

    // 1) idx_map = -1
    hipMemsetAsync(idx_map, 0xFF, (size_t)BB * HH * WW * sizeof(int), stream);
    // 2) scatter site ids
    smconv_scatter<<<(n + 255) / 256, 256, 0, stream>>>(idx, idx_map, n);
    // 3) transpose weights to (tap, C)
    smconv_wt<<<(KK * KK * CC + 255) / 256, 256, 0, stream>>>(w, w_t);
    // 4) lane-per-site conv: one block per region x channel chunk
    smconv_lane<<<NBLK, NT, 0, stream>>>(feat, w_t, bias, idx_map, out);
}

// Round 11
// 254.054 us; speedup vs baseline: 2.6077x; 2.6077x over previous
//
#include <hip/hip_runtime.h>

#define BB 4
#define HH 512
#define WW 512
#define KK 7
#define PP 3
#define CC 256
#define RH 64                  // region height
#define RW 32                  // region width
#define SH (RH + 2 * PP)       // 70
#define SW (RW + 2 * PP)       // 38
#define NT 512                 // threads per block (8 waves)
#define NWAVE (NT / 64)        // 8
#define NCHUNK 2
#define CHF 128                // floats per chunk (lane owns float2)
#define NREGN (BB * (HH / RH) * (WW / RW))   // 512
#define NBLK (NREGN * NCHUNK)                // 1024

// Scatter active-site linear index into dense idx_map (pre-filled with -1).
__global__ void smconv_scatter(const int* __restrict__ idx,
                               int* __restrict__ idx_map, int n) {
    int i = blockIdx.x * blockDim.x + threadIdx.x;
    if (i >= n) return;
    int b = idx[i * 3 + 0];
    int y = idx[i * 3 + 1];
    int x = idx[i * 3 + 2];
    idx_map[((size_t)b * HH + y) * WW + x] = i;
}

// Transpose weight (C, K, K) -> (K*K, C) so channel-major loads coalesce.
__global__ void smconv_wt(const float* __restrict__ w, float* __restrict__ w_t) {
    int i = blockIdx.x * blockDim.x + threadIdx.x;
    if (i >= KK * KK * CC) return;
    int tap = i / CC;
    int c = i - tap * CC;
    w_t[i] = w[c * KK * KK + tap];
}

// Block = 64x32 region x 128-channel chunk (1024 blocks, 4/CU, 32 waves/CU).
// Wave = site (R4 compute shape), lane = float2 of the chunk; 4-deep peel;
// readlane SGPR bases; chunk weights in LDS. Channel-split halves the
// per-XCD hot gather window so L2 captures the 9.4x spatial reuse (R7 mech).
__global__ void __launch_bounds__(NT, 8)
smconv_conv_c2(const float* __restrict__ feat,
               const float* __restrict__ w_t,
               const float* __restrict__ bias,
               const int* __restrict__ idx_map,
               float* __restrict__ out) {
    __shared__ int smap[SH * SW];                 // 10,640 B
    __shared__ unsigned short lst[RH * RW];       //  4,096 B
    __shared__ int wcnt[NWAVE];
    __shared__ float w_lds[KK * KK * CHF];        // 25,088 B

    const int tid  = threadIdx.x;
    const int wave = tid >> 6;
    const int lane = tid & 63;

    // XCD-chunked swizzle: XCD k owns 128 consecutive work items; chunk is
    // fastest-varying so a region's chunk-pair lands on the same XCD, and
    // scan-order region neighbors (shared halo rows) are L2-neighbors.
    const int Wk    = (blockIdx.x & 7) * (NBLK / 8) + (blockIdx.x >> 3);
    const int reg   = Wk >> 1;
    const int chunk = Wk & 1;
    const int b  = reg >> 7;              // 128 regions per batch
    const int rm = reg & 127;
    const int rx = rm >> 3;               // 16 column strips
    const int ry = rm & 7;                // y-adjacent regions consecutive
    const int y0 = ry * RH;
    const int x0 = rx * RW;

    // Stage this chunk's weights into LDS (float4-coalesced).
    for (int i = tid; i < KK * KK * CHF / 4; i += NT) {
        int t = i >> 5, j = i & 31;       // CHF/4 == 32
        ((float4*)w_lds)[i] =
            ((const float4*)w_t)[t * (CC / 4) + chunk * (CHF / 4) + j];
    }

    // Stage region+halo idx_map into LDS (-1 outside image).
    for (int i = tid; i < SH * SW; i += NT) {
        int gy = y0 + i / SW - PP;
        int gx = x0 + i % SW - PP;
        int v = -1;
        if (gy >= 0 && gy < HH && gx >= 0 && gx < WW)
            v = idx_map[((size_t)b * HH + gy) * WW + gx];
        smap[i] = v;
    }
    __syncthreads();

    // Build active-site list in deterministic scan order.
    int total = 0;
    for (int c0 = 0; c0 < RH * RW; c0 += NT) {
        int i = c0 + tid;
        int iy = i >> 5;
        int ix = i & (RW - 1);
        bool act = smap[(iy + PP) * SW + (ix + PP)] >= 0;
        unsigned long long bal = __ballot(act);
        if (lane == 0) wcnt[wave] = __popcll(bal);
        __syncthreads();
        int off = total;
        for (int w = 0; w < wave; ++w) off += wcnt[w];
        if (act)
            lst[off + __popcll(bal & ((1ull << lane) - 1))] = (unsigned short)i;
        int t2 = total;
        for (int w = 0; w < NWAVE; ++w) t2 += wcnt[w];
        total = t2;
        __syncthreads();
    }

    const int dy = lane / KK;   // tap row (lane < 49)
    const int dx = lane % KK;   // tap col
    const float2* feat2 = (const float2*)feat;
    const float2* wlds2 = (const float2*)w_lds;
    float2* out2 = (float2*)out;
    const int co = chunk * (CHF / 2) + lane;    // float2 offset within a row
    const float2 bv = ((const float2*)bias)[co];

    for (int e = wave; e < total; e += NWAVE) {
        const int pos = lst[e];
        const int iy = pos >> 5;
        const int ix = pos & (RW - 1);

        int nb = -1;
        if (lane < KK * KK)
            nb = smap[(iy + dy) * SW + (ix + dx)];

        const int site = __builtin_amdgcn_readlane(nb, PP * KK + PP);
        unsigned long long mask = __ballot(nb >= 0);

        float2 acc = make_float2(0.f, 0.f);

        while (mask) {
            // Peel up to 4 taps; dummies repeat t0 (L1-hot), FMAs predicated.
            int t0 = __ffsll((long long)mask) - 1; mask &= mask - 1;
            bool h1 = mask != 0;
            int t1 = h1 ? __ffsll((long long)mask) - 1 : t0; if (h1) mask &= mask - 1;
            bool h2 = mask != 0;
            int t2 = h2 ? __ffsll((long long)mask) - 1 : t0; if (h2) mask &= mask - 1;
            bool h3 = mask != 0;
            int t3 = h3 ? __ffsll((long long)mask) - 1 : t0; if (h3) mask &= mask - 1;

            int n0 = __builtin_amdgcn_readlane(nb, t0);
            int n1 = __builtin_amdgcn_readlane(nb, t1);
            int n2 = __builtin_amdgcn_readlane(nb, t2);
            int n3 = __builtin_amdgcn_readlane(nb, t3);

            float2 f0 = feat2[(size_t)n0 * (CC / 2) + co];
            float2 f1 = feat2[(size_t)n1 * (CC / 2) + co];
            float2 f2 = feat2[(size_t)n2 * (CC / 2) + co];
            float2 f3 = feat2[(size_t)n3 * (CC / 2) + co];

            float2 w0 = wlds2[t0 * (CHF / 2) + lane];
            float2 w1 = wlds2[t1 * (CHF / 2) + lane];
            float2 w2 = wlds2[t2 * (CHF / 2) + lane];
            float2 w3 = wlds2[t3 * (CHF / 2) + lane];

            acc.x = fmaf(f0.x, w0.x, acc.x);
            acc.y = fmaf(f0.y, w0.y, acc.y);
            if (h1) {
                acc.x = fmaf(f1.x, w1.x, acc.x);
                acc.y = fmaf(f1.y, w1.y, acc.y);
            }
            if (h2) {
                acc.x = fmaf(f2.x, w2.x, acc.x);
                acc.y = fmaf(f2.y, w2.y, acc.y);
            }
            if (h3) {
                acc.x = fmaf(f3.x, w3.x, acc.x);
                acc.y = fmaf(f3.y, w3.y, acc.y);
            }
        }

        out2[(size_t)site * (CC / 2) + co] = make_float2(acc.x + bv.x,
                                                         acc.y + bv.y);
    }
}

extern "C" void kernel_launch(void* const* d_in, const int* in_sizes, int n_in,
                              void* d_out, int out_size, void* d_ws, size_t ws_size,
                              hipStream_t stream) {
    const float* feat = (const float*)d_in[0];
    const int*   idx  = (const int*)d_in[1];
    const float* w    = (const float*)d_in[2];
    const float* bias = (const float*)d_in[3];
    float* out = (float*)d_out;

    const int n = in_sizes[0] / CC;  // number of active sites

    int*   idx_map = (int*)d_ws;
    float* w_t     = (float*)((char*)d_ws + (size_t)BB * HH * WW * sizeof(int));

    // 1) idx_map = -1
    hipMemsetAsync(idx_map, 0xFF, (size_t)BB * HH * WW * sizeof(int), stream);
    // 2) scatter site ids
    smconv_scatter<<<(n + 255) / 256, 256, 0, stream>>>(idx, idx_map, n);
    // 3) transpose weights to (tap, C)
    smconv_wt<<<(KK * KK * CC + 255) / 256, 256, 0, stream>>>(w, w_t);
    // 4) chunked region conv: 512 regions x 2 chunks, 4 blocks/CU
    smconv_conv_c2<<<NBLK, NT, 0, stream>>>(feat, w_t, bias, idx_map, out);
}

// Round 12
// 250.230 us; speedup vs baseline: 2.6475x; 1.0153x over previous
//
#include <hip/hip_runtime.h>

#define BB 4
#define HH 512
#define WW 512
#define KK 7
#define PP 3
#define CC 256
#define RH 64                  // region height
#define RW 32                  // region width
#define SH (RH + 2 * PP)       // 70
#define SW (RW + 2 * PP)       // 38
#define NT 1024                // threads per block
#define NWAVE (NT / 64)        // 16
#define NREG (BB * (HH / RH) * (WW / RW))   // 512

// Scatter active-site linear index into dense idx_map (pre-filled with -1).
__global__ void smconv_scatter(const int* __restrict__ idx,
                               int* __restrict__ idx_map, int n) {
    int i = blockIdx.x * blockDim.x + threadIdx.x;
    if (i >= n) return;
    int b = idx[i * 3 + 0];
    int y = idx[i * 3 + 1];
    int x = idx[i * 3 + 2];
    idx_map[((size_t)b * HH + y) * WW + x] = i;
}

// Transpose weight (C, K, K) -> (K*K, C) so channel-major loads coalesce.
__global__ void smconv_wt(const float* __restrict__ w, float* __restrict__ w_t) {
    int i = blockIdx.x * blockDim.x + threadIdx.x;
    if (i >= KK * KK * CC) return;
    int tap = i / CC;
    int c = i - tap * CC;
    w_t[i] = w[c * KK * KK + tap];
}

// R4 geometry (64x32 regions, 2 blocks/CU) but TWO sequential channel passes
// per block: pass p covers channels [128p, 128p+128), lane owns a float2.
// Each pass's live-row window is ~35KB/block -> ~2.2MB/XCD < 4MiB L2, so the
// 9.4x spatial reuse of each cache line is served by L2, not L3.
__global__ void __launch_bounds__(NT, 8)
smconv_conv_2p(const float* __restrict__ feat,
               const float* __restrict__ w_t,
               const float* __restrict__ bias,
               const int* __restrict__ idx_map,
               float* __restrict__ out) {
    __shared__ int smap[SH * SW];                 // 10,640 B
    __shared__ unsigned short lst[RH * RW];       //  4,096 B
    __shared__ int wcnt[NWAVE];
    __shared__ float w_lds[KK * KK * CC];         // 50,176 B

    const int tid  = threadIdx.x;
    const int wave = tid >> 6;
    const int lane = tid & 63;

    // XCD-chunked swizzle: XCD k owns 64 contiguous scan-ordered regions.
    const int r  = (blockIdx.x & 7) * 64 + (blockIdx.x >> 3);
    const int b  = r >> 7;              // 128 regions per batch
    const int rm = r & 127;
    const int rx = rm >> 3;             // 16 column strips
    const int ry = rm & 7;              // y-adjacent regions consecutive
    const int y0 = ry * RH;
    const int x0 = rx * RW;

    // Stage full weights (tap, C) into LDS, coalesced float4.
    for (int i = tid; i < KK * KK * CC / 4; i += NT)
        ((float4*)w_lds)[i] = ((const float4*)w_t)[i];

    // Stage region+halo idx_map into LDS (-1 outside image).
    for (int i = tid; i < SH * SW; i += NT) {
        int gy = y0 + i / SW - PP;
        int gx = x0 + i % SW - PP;
        int v = -1;
        if (gy >= 0 && gy < HH && gx >= 0 && gx < WW)
            v = idx_map[((size_t)b * HH + gy) * WW + gx];
        smap[i] = v;
    }
    __syncthreads();

    // Build active-site list in deterministic scan order.
    int total = 0;
    for (int c0 = 0; c0 < RH * RW; c0 += NT) {
        int i = c0 + tid;
        int iy = i >> 5;
        int ix = i & (RW - 1);
        bool act = smap[(iy + PP) * SW + (ix + PP)] >= 0;
        unsigned long long bal = __ballot(act);
        if (lane == 0) wcnt[wave] = __popcll(bal);
        __syncthreads();
        int off = total;
        for (int w = 0; w < wave; ++w) off += wcnt[w];
        if (act)
            lst[off + __popcll(bal & ((1ull << lane) - 1))] = (unsigned short)i;
        int t2 = total;
        for (int w = 0; w < NWAVE; ++w) t2 += wcnt[w];
        total = t2;
        __syncthreads();
    }

    const int dy = lane / KK;   // tap row (lane < 49)
    const int dx = lane % KK;   // tap col
    const float2* feat2 = (const float2*)feat;
    const float2* wlds2 = (const float2*)w_lds;
    const float2* bias2 = (const float2*)bias;
    float2* out2 = (float2*)out;

    #pragma unroll 1
    for (int pass = 0; pass < 2; ++pass) {
        const int co = pass * 64 + lane;        // float2 index within a row
        const float2 bv = bias2[co];

        for (int e = wave; e < total; e += NWAVE) {
            const int pos = lst[e];
            const int iy = pos >> 5;
            const int ix = pos & (RW - 1);

            int nb = -1;
            if (lane < KK * KK)
                nb = smap[(iy + dy) * SW + (ix + dx)];

            const int site = __builtin_amdgcn_readlane(nb, PP * KK + PP);
            unsigned long long mask = __ballot(nb >= 0);

            float2 acc = make_float2(0.f, 0.f);

            while (mask) {
                // Peel up to 4 taps; dummies repeat t0 (L1-hot), FMAs off.
                int t0 = __ffsll((long long)mask) - 1; mask &= mask - 1;
                bool h1 = mask != 0;
                int t1 = h1 ? __ffsll((long long)mask) - 1 : t0; if (h1) mask &= mask - 1;
                bool h2 = mask != 0;
                int t2 = h2 ? __ffsll((long long)mask) - 1 : t0; if (h2) mask &= mask - 1;
                bool h3 = mask != 0;
                int t3 = h3 ? __ffsll((long long)mask) - 1 : t0; if (h3) mask &= mask - 1;

                int n0 = __builtin_amdgcn_readlane(nb, t0);
                int n1 = __builtin_amdgcn_readlane(nb, t1);
                int n2 = __builtin_amdgcn_readlane(nb, t2);
                int n3 = __builtin_amdgcn_readlane(nb, t3);

                float2 f0 = feat2[(size_t)n0 * (CC / 2) + co];
                float2 f1 = feat2[(size_t)n1 * (CC / 2) + co];
                float2 f2 = feat2[(size_t)n2 * (CC / 2) + co];
                float2 f3 = feat2[(size_t)n3 * (CC / 2) + co];

                float2 w0 = wlds2[t0 * (CC / 2) + co];
                float2 w1 = wlds2[t1 * (CC / 2) + co];
                float2 w2 = wlds2[t2 * (CC / 2) + co];
                float2 w3 = wlds2[t3 * (CC / 2) + co];

                acc.x = fmaf(f0.x, w0.x, acc.x);
                acc.y = fmaf(f0.y, w0.y, acc.y);
                if (h1) {
                    acc.x = fmaf(f1.x, w1.x, acc.x);
                    acc.y = fmaf(f1.y, w1.y, acc.y);
                }
                if (h2) {
                    acc.x = fmaf(f2.x, w2.x, acc.x);
                    acc.y = fmaf(f2.y, w2.y, acc.y);
                }
                if (h3) {
                    acc.x = fmaf(f3.x, w3.x, acc.x);
                    acc.y = fmaf(f3.y, w3.y, acc.y);
                }
            }

            out2[(size_t)site * (CC / 2) + co] = make_float2(acc.x + bv.x,
                                                             acc.y + bv.y);
        }
    }
}

extern "C" void kernel_launch(void* const* d_in, const int* in_sizes, int n_in,
                              void* d_out, int out_size, void* d_ws, size_t ws_size,
                              hipStream_t stream) {
    const float* feat = (const float*)d_in[0];
    const int*   idx  = (const int*)d_in[1];
    const float* w    = (const float*)d_in[2];
    const float* bias = (const float*)d_in[3];
    float* out = (float*)d_out;

    const int n = in_sizes[0] / CC;  // number of active sites

    int*   idx_map = (int*)d_ws;
    float* w_t     = (float*)((char*)d_ws + (size_t)BB * HH * WW * sizeof(int));

    // 1) idx_map = -1
    hipMemsetAsync(idx_map, 0xFF, (size_t)BB * HH * WW * sizeof(int), stream);
    // 2) scatter site ids
    smconv_scatter<<<(n + 255) / 256, 256, 0, stream>>>(idx, idx_map, n);
    // 3) transpose weights to (tap, C)
    smconv_wt<<<(KK * KK * CC + 255) / 256, 256, 0, stream>>>(w, w_t);
    // 4) two-pass chunked region conv: 512 blocks, 2/CU
    smconv_conv_2p<<<NREG, NT, 0, stream>>>(feat, w_t, bias, idx_map, out);
}